// Round 13
// baseline (3118.348 us; speedup 1.0000x reference)
//
#include <hip/hip_runtime.h>
#include <hip/hip_bf16.h>
#include <math.h>

#define L_ 12
#define B_ 4
#define T_ 1024
#define C_ 768
#define H_ 12
#define D_ 64
#define V_ 50257
#define M_ 4096
#define QKVN 2304
#define FF_ 3072
#define VPAD_ 51200   // 200 n-tiles of 256 (XCD-partitioned head mapping)

typedef __hip_bfloat16 bf16;
typedef __attribute__((ext_vector_type(4))) float f32x4;
typedef __attribute__((ext_vector_type(4))) short short4v;
typedef __attribute__((ext_vector_type(8))) short short8;
typedef __attribute__((ext_vector_type(8))) __bf16 bf16x8;

typedef __attribute__((address_space(1))) void gvoid;
typedef __attribute__((address_space(3))) void svoid;

__device__ __forceinline__ f32x4 mfma_bf16(short8 a, short8 b, f32x4 c) {
  return __builtin_amdgcn_mfma_f32_16x16x32_bf16(
      __builtin_bit_cast(bf16x8, a), __builtin_bit_cast(bf16x8, b), c, 0, 0, 0);
}

__device__ __forceinline__ void gload_lds16(const void* g, void* l) {
  __builtin_amdgcn_global_load_lds((gvoid*)(void*)g, (svoid*)l, 16, 0, 0);
}

__device__ __forceinline__ short f2bf(float x) {
  return __builtin_bit_cast(short, __float2bfloat16(x));
}

// ---------------- embedding ----------------
__global__ __launch_bounds__(256) void embed_kernel(const int* __restrict__ idx,
    const float* __restrict__ tok, const float* __restrict__ pos, float* __restrict__ x)
{
  const int row = blockIdx.x;
  const int t = row & (T_ - 1);
  const int id = idx[row];
  const float* te = tok + (size_t)id * C_;
  const float* pe = pos + (size_t)t * C_;
  float* xr = x + (size_t)row * C_;
  const int tid = threadIdx.x;
  xr[tid]       = te[tid]       + pe[tid];
  xr[tid + 256] = te[tid + 256] + pe[tid + 256];
  xr[tid + 512] = te[tid + 512] + pe[tid + 512];
}

// ---------------- layernorm: 1 wave/row, float4 loads, shuffle-only reduce ----------------
__global__ __launch_bounds__(256) void ln_kernel(const float* __restrict__ x,
    const float* __restrict__ g, const float* __restrict__ be, bf16* __restrict__ out)
{
  const int w = threadIdx.x >> 6, l = threadIdx.x & 63;
  const int row = blockIdx.x * 4 + w;
  const float* xr = x + (size_t)row * C_;
  f32x4 v[3];
  float s = 0.0f, ss = 0.0f;
#pragma unroll
  for (int p = 0; p < 3; p++) {
    v[p] = *(const f32x4*)&xr[p * 256 + l * 4];
#pragma unroll
    for (int e = 0; e < 4; e++) { s += v[p][e]; ss += v[p][e] * v[p][e]; }
  }
#pragma unroll
  for (int o = 32; o >= 1; o >>= 1) { s += __shfl_xor(s, o, 64); ss += __shfl_xor(ss, o, 64); }
  const float mean = s * (1.0f / C_);
  const float rstd = rsqrtf(ss * (1.0f / C_) - mean * mean + 1e-5f);
  bf16* orow = out + (size_t)row * C_;
#pragma unroll
  for (int p = 0; p < 3; p++) {
    const f32x4 gg = *(const f32x4*)&g[p * 256 + l * 4];
    const f32x4 bb = *(const f32x4*)&be[p * 256 + l * 4];
    short4v o4;
#pragma unroll
    for (int e = 0; e < 4; e++) o4[e] = f2bf((v[p][e] - mean) * rstd * gg[e] + bb[e]);
    *(short4v*)&orow[p * 256 + l * 4] = o4;
  }
}

// ---------------- weight convert + transpose: fp32 [K][N] -> bf16 [N(+pad)][K] ----------------
__global__ __launch_bounds__(256) void convt_kernel(const float* __restrict__ in,
    bf16* __restrict__ out, int K, int N, long in_ls, long out_ls, int row_off)
{
  __shared__ float tile[64][65];
  in  += (size_t)blockIdx.z * in_ls;
  out += (size_t)blockIdx.z * out_ls;
  const int k0 = blockIdx.x * 64, n0 = blockIdx.y * 64;
  const int tid = threadIdx.x;
#pragma unroll
  for (int ph = 0; ph < 4; ph++) {
    const int lk = ph * 16 + (tid >> 4);
    const int ln = (tid & 15) * 4;
    const int gn = n0 + ln;
    const float* src = &in[(size_t)(k0 + lk) * N + gn];
    f32x4 vv;
    if (gn + 4 <= N) {
      vv = *(const f32x4*)src;
    } else {
#pragma unroll
      for (int e = 0; e < 4; e++) vv[e] = (gn + e < N) ? src[e] : 0.0f;
    }
    *(f32x4*)&tile[lk][ln] = vv;
  }
  __syncthreads();
#pragma unroll
  for (int ph = 0; ph < 2; ph++) {
    const int lon = ph * 32 + (tid >> 3);
    const int lok0 = (tid & 7) * 8;
    short8 o;
#pragma unroll
    for (int e = 0; e < 8; e++) o[e] = f2bf(tile[lok0 + e][lon]);
    *(short8*)&out[(size_t)(row_off + n0 + lon) * K + k0 + lok0] = o;
  }
}

// ---------------- pack q/k/v biases into [L][2304] ----------------
__global__ __launch_bounds__(256) void packb_kernel(const float* __restrict__ bq,
    const float* __restrict__ bk, const float* __restrict__ bv, float* __restrict__ out)
{
  const int i = blockIdx.x * 256 + threadIdx.x;
  const int ly = i / QKVN, c = i % QKVN;
  float v;
  if (c < C_)            v = bq[ly * C_ + c];
  else if (c < 2 * C_)   v = bk[ly * C_ + c - C_];
  else                   v = bv[ly * C_ + c - 2 * C_];
  out[i] = v;
}

// ---------------- GEMM 128x128 tile (kept for reference shapes) ----------------
template<bool BIAS, bool GELU, bool RESID, bool BF16OUT, bool VT>
__global__ __launch_bounds__(256) void gemm_bt(
    const short* __restrict__ A, const short* __restrict__ Bt,
    const float* __restrict__ bias, const float* resid,
    void* out, short* __restrict__ vt, int M, int N, int K)
{
  __shared__ short As[128 * 64];
  __shared__ short Bs[128 * 64];
  const int tid = threadIdx.x;
  const int w = tid >> 6, l = tid & 63;
  const int l15 = l & 15, l4 = l >> 4;
  const int wr = w >> 1, wc = w & 1;
  const int nwg = gridDim.x * gridDim.y;
  const int id = blockIdx.y * gridDim.x + blockIdx.x;
  const int chunk = nwg >> 3;
  const int swz = (id & 7) * chunk + (id >> 3);
  const long m0 = (long)(swz % gridDim.x) * 128;
  const long n0 = (long)(swz / gridDim.x) * 128;

  f32x4 acc[4][4] = {};
  const int lrow8 = l >> 3;
  const int lc = l & 7;

  for (int kt = 0; kt < K; kt += 64) {
#pragma unroll
    for (int j = 0; j < 8; j++) {
      const int c = w * 8 + j;
      const int isA = (c < 16);
      const int cc = isA ? c : (c - 16);
      const int row = cc * 8 + lrow8;
      const int colsw = ((lc ^ (row & 7)) << 3);
      const short* gp = (isA ? A + (size_t)(m0 + row) * K : Bt + (size_t)(n0 + row) * K) + kt + colsw;
      short* sp = (isA ? As : Bs) + row * 64 + (lc << 3);
      gload_lds16(gp, sp);
    }
    __syncthreads();
#pragma unroll
    for (int ks = 0; ks < 2; ks++) {
      short8 af[4], bfr[4];
#pragma unroll
      for (int i = 0; i < 4; i++) {
        int row = wr * 64 + i * 16 + l15;
        int cs = (ks * 32 + l4 * 8) ^ ((row & 7) << 3);
        af[i] = *(const short8*)&As[row * 64 + cs];
      }
#pragma unroll
      for (int jn = 0; jn < 4; jn++) {
        int row = wc * 64 + jn * 16 + l15;
        int cs = (ks * 32 + l4 * 8) ^ ((row & 7) << 3);
        bfr[jn] = *(const short8*)&Bs[row * 64 + cs];
      }
#pragma unroll
      for (int i = 0; i < 4; i++)
#pragma unroll
        for (int jn = 0; jn < 4; jn++)
          acc[i][jn] = mfma_bf16(af[i], bfr[jn], acc[i][jn]);
    }
    __syncthreads();
  }

#pragma unroll
  for (int i = 0; i < 4; i++) {
    const long rbase = m0 + wr * 64 + i * 16 + l4 * 4;
#pragma unroll
    for (int jn = 0; jn < 4; jn++) {
      const long col = n0 + wc * 64 + jn * 16 + l15;
      const float bv = BIAS ? bias[col] : 0.0f;
      if (VT && col >= 2 * C_) {
        const int hd = (int)col - 2 * C_;
        const int b = (int)(rbase >> 10);
        const int t0 = (int)(rbase & 1023);
        short4v o4;
#pragma unroll
        for (int r = 0; r < 4; r++) o4[r] = f2bf(acc[i][jn][r] + bv);
        *(short4v*)&vt[((size_t)(b * H_) * D_ + hd) * T_ + t0] = o4;
      } else {
#pragma unroll
        for (int r = 0; r < 4; r++) {
          float v = acc[i][jn][r] + bv;
          if (GELU) v = 0.5f * v * (1.0f + erff(v * 0.70710678118654752f));
          const size_t o = (size_t)(rbase + r) * (size_t)N + col;
          if (RESID)        ((float*)out)[o] = resid[o] + v;
          else if (BF16OUT) ((bf16*)out)[o] = __float2bfloat16(v);
          else              ((float*)out)[o] = v;
        }
      }
    }
  }
}

// ---------------- GEMM 64x128 tile (qkv w/ fused V-transpose, fc1, proj, fc2) ----------------
template<bool BIAS, bool GELU, bool RESID, bool BF16OUT, bool VT>
__global__ __launch_bounds__(256) void gemm64(
    const short* __restrict__ A, const short* __restrict__ Bt,
    const float* __restrict__ bias, const float* resid,
    void* out, short* __restrict__ vt, int M, int N, int K)
{
  __shared__ short As[64 * 64];
  __shared__ short Bs[128 * 64];
  const int tid = threadIdx.x;
  const int w = tid >> 6, l = tid & 63;
  const int l15 = l & 15, l4 = l >> 4;
  const int wm = w >> 1, wn = w & 1;
  const int nwg = gridDim.x * gridDim.y;
  const int id = blockIdx.y * gridDim.x + blockIdx.x;
  const int chunk = nwg >> 3;
  const int swz = (id & 7) * chunk + (id >> 3);
  const long m0 = (long)(swz % gridDim.x) * 64;
  const long n0 = (long)(swz / gridDim.x) * 128;
  const int rr = tid >> 3, g = tid & 7;

  f32x4 acc[2][4] = {};

  for (int kt = 0; kt < K; kt += 64) {
#pragma unroll
    for (int p = 0; p < 2; p++) {
      const int row = p * 32 + rr;
      const int cg = ((g ^ (row & 7)) << 3);
      gload_lds16(A + (size_t)(m0 + row) * K + kt + cg, &As[row * 64 + g * 8]);
    }
#pragma unroll
    for (int p = 0; p < 4; p++) {
      const int row = p * 32 + rr;
      const int cg = ((g ^ (row & 7)) << 3);
      gload_lds16(Bt + (size_t)(n0 + row) * K + kt + cg, &Bs[row * 64 + g * 8]);
    }
    __syncthreads();
#pragma unroll
    for (int ks = 0; ks < 2; ks++) {
      short8 af[2], bfr[4];
#pragma unroll
      for (int i = 0; i < 2; i++) {
        int row = wm * 32 + i * 16 + l15;
        int cs = (ks * 32 + l4 * 8) ^ ((row & 7) << 3);
        af[i] = *(const short8*)&As[row * 64 + cs];
      }
#pragma unroll
      for (int j = 0; j < 4; j++) {
        int row = wn * 64 + j * 16 + l15;
        int cs = (ks * 32 + l4 * 8) ^ ((row & 7) << 3);
        bfr[j] = *(const short8*)&Bs[row * 64 + cs];
      }
#pragma unroll
      for (int i = 0; i < 2; i++)
#pragma unroll
        for (int j = 0; j < 4; j++)
          acc[i][j] = mfma_bf16(af[i], bfr[j], acc[i][j]);
    }
    __syncthreads();
  }

#pragma unroll
  for (int i = 0; i < 2; i++) {
    const long rbase = m0 + wm * 32 + i * 16 + l4 * 4;
#pragma unroll
    for (int j = 0; j < 4; j++) {
      const long col = n0 + wn * 64 + j * 16 + l15;
      const float bv = BIAS ? bias[col] : 0.0f;
      if (VT && col >= 2 * C_) {
        const int hd = (int)col - 2 * C_;
        const int b = (int)(rbase >> 10);
        const int t0 = (int)(rbase & 1023);
        short4v o4;
#pragma unroll
        for (int r = 0; r < 4; r++) o4[r] = f2bf(acc[i][j][r] + bv);
        *(short4v*)&vt[((size_t)(b * H_) * D_ + hd) * T_ + t0] = o4;
      } else {
#pragma unroll
        for (int r = 0; r < 4; r++) {
          float v = acc[i][j][r] + bv;
          if (GELU) v = 0.5f * v * (1.0f + erff(v * 0.70710678118654752f));
          const size_t o = (size_t)(rbase + r) * (size_t)N + col;
          if (RESID)        ((float*)out)[o] = resid[o] + v;
          else if (BF16OUT) ((bf16*)out)[o] = __float2bfloat16(v);
          else              ((float*)out)[o] = v;
        }
      }
    }
  }
}

// ---------------- 256x256 pipelined head GEMM: vmcnt(6) pipeline + XCD m/n partition ----------
__global__ __launch_bounds__(512, 1) void gemm256(
    const short* __restrict__ A, const short* __restrict__ Bt,
    float* __restrict__ out, int N, int K)
{
  __shared__ short As[2][256 * 64];
  __shared__ short Bs[2][256 * 64];
  const int tid = threadIdx.x;
  const int l = tid & 63, l15 = l & 15, l4 = l >> 4;
  const int wv = tid >> 6, wm = wv >> 2, wn = wv & 3;
  const int bid = blockIdx.x;
  const int x = bid & 7, r = bid >> 3;
  const int mt = (x & 1) * 8 + (r & 7);
  const int nt = (x >> 1) * 50 + (r >> 3);
  const long m0 = (long)mt * 256;
  const long n0 = (long)nt * 256;
  const int nkt = K >> 6;
  const int rr = tid >> 3, g = tid & 7;

  f32x4 acc[8][4] = {};

  auto stA = [&](int s, int kt, int off) {
#pragma unroll
    for (int p = 0; p < 2; p++) {
      const int row = p * 128 + off + rr;
      gload_lds16(A + (size_t)(m0 + row) * K + (kt << 6) + ((g ^ (row & 7)) << 3),
                  &As[s][row * 64 + g * 8]);
    }
  };
  auto stB = [&](int s, int kt, int off) {
#pragma unroll
    for (int p = 0; p < 2; p++) {
      const int row = p * 128 + ((rr >> 5) << 6) + (rr & 31) + off;
      gload_lds16(Bt + (size_t)(n0 + row) * K + (kt << 6) + ((g ^ (row & 7)) << 3),
                  &Bs[s][row * 64 + g * 8]);
    }
  };
  auto rdA = [&](int s, int mf, int ks) {
    const int row = wm * 128 + mf * 16 + l15;
    const int cs = (ks * 32 + l4 * 8) ^ ((row & 7) << 3);
    return *(const short8*)&As[s][row * 64 + cs];
  };
  auto rdB = [&](int s, int nf, int ks) {
    const int row = wn * 64 + nf * 16 + l15;
    const int cs = (ks * 32 + l4 * 8) ^ ((row & 7) << 3);
    return *(const short8*)&Bs[s][row * 64 + cs];
  };

  stA(0, 0, 0); stB(0, 0, 0); stA(0, 0, 64); stB(0, 0, 32);

  int q = 0;
  for (int kt = 0; kt < nkt; ++kt, q ^= 1) {
    const int ktn = (kt + 1 < nkt) ? kt + 1 : kt;
    short8 a0[2][4], a1[2][4], b0[2][2], b1[2][2];

    stA(q ^ 1, ktn, 0);
    asm volatile("s_waitcnt vmcnt(6)" ::: "memory");
    __builtin_amdgcn_s_barrier();
#pragma unroll
    for (int ks = 0; ks < 2; ks++) {
#pragma unroll
      for (int f = 0; f < 4; f++) a0[ks][f] = rdA(q, f, ks);
#pragma unroll
      for (int j = 0; j < 2; j++) b0[ks][j] = rdB(q, j, ks);
    }
    __builtin_amdgcn_s_setprio(1);
#pragma unroll
    for (int f = 0; f < 4; f++)
#pragma unroll
      for (int j = 0; j < 2; j++) {
        acc[f][j] = mfma_bf16(a0[0][f], b0[0][j], acc[f][j]);
        acc[f][j] = mfma_bf16(a0[1][f], b0[1][j], acc[f][j]);
      }
    __builtin_amdgcn_s_setprio(0);

    stB(q ^ 1, ktn, 0);
    asm volatile("s_waitcnt vmcnt(6)" ::: "memory");
    __builtin_amdgcn_s_barrier();
#pragma unroll
    for (int ks = 0; ks < 2; ks++)
#pragma unroll
      for (int f = 0; f < 4; f++) a1[ks][f] = rdA(q, f + 4, ks);
    __builtin_amdgcn_s_setprio(1);
#pragma unroll
    for (int f = 0; f < 4; f++)
#pragma unroll
      for (int j = 0; j < 2; j++) {
        acc[f + 4][j] = mfma_bf16(a1[0][f], b0[0][j], acc[f + 4][j]);
        acc[f + 4][j] = mfma_bf16(a1[1][f], b0[1][j], acc[f + 4][j]);
      }
    __builtin_amdgcn_s_setprio(0);

    stA(q ^ 1, ktn, 64);
    asm volatile("s_waitcnt vmcnt(6)" ::: "memory");
    __builtin_amdgcn_s_barrier();
#pragma unroll
    for (int ks = 0; ks < 2; ks++)
#pragma unroll
      for (int j = 0; j < 2; j++) b1[ks][j] = rdB(q, j + 2, ks);
    __builtin_amdgcn_s_setprio(1);
#pragma unroll
    for (int f = 0; f < 4; f++)
#pragma unroll
      for (int j = 0; j < 2; j++) {
        acc[f][j + 2] = mfma_bf16(a0[0][f], b1[0][j], acc[f][j + 2]);
        acc[f][j + 2] = mfma_bf16(a0[1][f], b1[1][j], acc[f][j + 2]);
      }
    __builtin_amdgcn_s_setprio(0);

    stB(q ^ 1, ktn, 32);
    __builtin_amdgcn_s_setprio(1);
#pragma unroll
    for (int f = 0; f < 4; f++)
#pragma unroll
      for (int j = 0; j < 2; j++) {
        acc[f + 4][j + 2] = mfma_bf16(a1[0][f], b1[0][j], acc[f + 4][j + 2]);
        acc[f + 4][j + 2] = mfma_bf16(a1[1][f], b1[1][j], acc[f + 4][j + 2]);
      }
    __builtin_amdgcn_s_setprio(0);
  }

#pragma unroll
  for (int i = 0; i < 8; i++) {
#pragma unroll
    for (int j = 0; j < 4; j++) {
      const long col = n0 + wn * 64 + j * 16 + l15;
      if (col >= N) continue;
#pragma unroll
      for (int r2 = 0; r2 < 4; r2++) {
        const long row = m0 + wm * 128 + i * 16 + l4 * 4 + r2;
        out[(size_t)row * (size_t)N + col] = acc[i][j][r2];
      }
    }
  }
}

// ---------------- flash attention: swapped QK^T, lane-local softmax, defer-max (r11 winner) ----
__global__ __launch_bounds__(256) void attn_kernel(const short* __restrict__ qkv,
    const short* __restrict__ vt, bf16* __restrict__ y)
{
  __shared__ short Ks[2][64 * 64];
  __shared__ short Vs[2][64 * 64];
  const int qt = (gridDim.x - 1) - blockIdx.x;
  const int bh = blockIdx.y;
  const int b = bh / H_, h = bh % H_;
  const int tid = threadIdx.x, w = tid >> 6, l = tid & 63;
  const int l15 = l & 15, l4 = l >> 4;
  const int qrow0 = qt * 64 + w * 16;
  const float SC2 = 0.125f * 1.44269504088896f;

  auto stageKV = [&](int s, int s0) {
    const short* kbase = qkv + (size_t)(b * T_ + s0) * QKVN + C_ + h * D_;
    const short* vsrc = vt + (size_t)bh * D_ * T_ + s0;
#pragma unroll
    for (int ph = 0; ph < 2; ph++) {
      int r = ph * 32 + (tid >> 3);
      int gk = ((tid & 7) ^ ((r & 3) | (((r >> 3) & 1) << 2))) << 3;
      int gv = ((tid & 7) ^ (r & 7)) << 3;
      gload_lds16(kbase + (size_t)r * QKVN + gk, &Ks[s][r * 64 + (tid & 7) * 8]);
      gload_lds16(vsrc + (size_t)r * T_ + gv, &Vs[s][r * 64 + (tid & 7) * 8]);
    }
  };

  short8 qf[2];
#pragma unroll
  for (int kf = 0; kf < 2; kf++)
    qf[kf] = *(const short8*)&qkv[(size_t)(b * T_ + qrow0 + l15) * QKVN + h * D_ + kf * 32 + l4 * 8];

  f32x4 O[4] = {};
  float mst = -1e30f, lst = 0.0f;

  stageKV(0, 0);
  __syncthreads();

  int cur = 0;
  const int qg = qrow0 + l15;
  const int send = qt * 64 + 64;
  for (int s0 = 0; s0 < send; s0 += 64) {
    if (s0 + 64 < send) stageKV(cur ^ 1, s0 + 64);
    f32x4 S[4];
#pragma unroll
    for (int c = 0; c < 4; c++) {
      const int row = 8 * (l15 >> 2) + (l15 & 3) + 4 * (c & 1) + 32 * (c >> 1);
      const int swz = (row & 3) | (((row >> 3) & 1) << 2);
      short8 k0 = *(const short8*)&Ks[cur][row * 64 + ((l4 ^ swz) << 3)];
      short8 k1 = *(const short8*)&Ks[cur][row * 64 + (((4 + l4) ^ swz) << 3)];
      f32x4 z = {0.0f, 0.0f, 0.0f, 0.0f};
      z = mfma_bf16(k0, qf[0], z);
      z = mfma_bf16(k1, qf[1], z);
      S[c] = z;
    }
#pragma unroll
    for (int c = 0; c < 4; c++) {
      const int kvb = s0 + 8 * l4 + 4 * (c & 1) + 32 * (c >> 1);
#pragma unroll
      for (int r = 0; r < 4; r++) {
        const float v = S[c][r] * SC2;
        S[c][r] = (kvb + r <= qg) ? v : -1e30f;
      }
    }
    float pm = -1e30f;
#pragma unroll
    for (int c = 0; c < 4; c++)
#pragma unroll
      for (int r = 0; r < 4; r++) pm = fmaxf(pm, S[c][r]);
    float mn;
    if (__all(pm - mst <= 8.0f)) {
      mn = mst;
    } else {
      float pm2 = fmaxf(pm, __shfl_xor(pm, 16, 64));
      pm2 = fmaxf(pm2, __shfl_xor(pm2, 32, 64));
      mn = fmaxf(mst, pm2);
      const float al = exp2f(mst - mn);
      mst = mn;
      lst *= al;
#pragma unroll
      for (int r = 0; r < 4; r++) {
        const float alr = __shfl(al, l4 * 4 + r, 16);
#pragma unroll
        for (int df = 0; df < 4; df++) O[df][r] *= alr;
      }
    }
    float rs = 0.0f;
    float pvv[4][4];
#pragma unroll
    for (int c = 0; c < 4; c++)
#pragma unroll
      for (int r = 0; r < 4; r++) { pvv[c][r] = exp2f(S[c][r] - mn); rs += pvv[c][r]; }
    rs += __shfl_xor(rs, 16, 64);
    rs += __shfl_xor(rs, 32, 64);
    lst += rs;
    short8 pa[2];
#pragma unroll
    for (int ks = 0; ks < 2; ks++)
#pragma unroll
      for (int r = 0; r < 4; r++) {
        pa[ks][r]     = f2bf(pvv[2 * ks][r]);
        pa[ks][r + 4] = f2bf(pvv[2 * ks + 1][r]);
      }
#pragma unroll
    for (int df = 0; df < 4; df++) {
      const int row = df * 16 + l15;
      short8 v0 = *(const short8*)&Vs[cur][row * 64 + ((l4 ^ (row & 7)) << 3)];
      short8 v1 = *(const short8*)&Vs[cur][row * 64 + ((((4 + l4)) ^ (row & 7)) << 3)];
      O[df] = mfma_bf16(pa[0], v0, O[df]);
      O[df] = mfma_bf16(pa[1], v1, O[df]);
    }
    __syncthreads();
    cur ^= 1;
  }

  const float inv = 1.0f / lst;
#pragma unroll
  for (int r = 0; r < 4; r++) {
    const float invr = __shfl(inv, l4 * 4 + r, 16);
    const size_t row = (size_t)(b * T_ + qrow0 + l4 * 4 + r);
#pragma unroll
    for (int df = 0; df < 4; df++)
      y[row * C_ + h * D_ + df * 16 + l15] = __float2bfloat16(O[df][r] * invr);
  }
}

// ---------------- host ----------------
extern "C" void kernel_launch(void* const* d_in, const int* in_sizes, int n_in,
                              void* d_out, int out_size, void* d_ws, size_t ws_size,
                              hipStream_t stream)
{
  const int*   idx  = (const int*)d_in[0];
  const float* tok  = (const float*)d_in[1];
  const float* pos  = (const float*)d_in[2];
  const float* wq   = (const float*)d_in[3];
  const float* bq   = (const float*)d_in[4];
  const float* wk   = (const float*)d_in[5];
  const float* bk   = (const float*)d_in[6];
  const float* wv   = (const float*)d_in[7];
  const float* bv   = (const float*)d_in[8];
  const float* wo   = (const float*)d_in[9];
  const float* bo   = (const float*)d_in[10];
  const float* ln1g = (const float*)d_in[11];
  const float* ln1b = (const float*)d_in[12];
  const float* ln2g = (const float*)d_in[13];
  const float* ln2b = (const float*)d_in[14];
  const float* w1   = (const float*)d_in[15];
  const float* b1   = (const float*)d_in[16];
  const float* w2   = (const float*)d_in[17];
  const float* b2   = (const float*)d_in[18];
  const float* lnfg = (const float*)d_in[19];
  const float* lnfb = (const float*)d_in[20];
  const float* headw= (const float*)d_in[21];

  char* p = (char*)d_ws;
  size_t off = 0;
  auto alloc = [&](size_t n) { void* r = p + off; off += (n + 255) & ~(size_t)255; return r; };
  short* qkvT  = (short*)alloc((size_t)L_ * QKVN * C_ * 2);
  short* woT   = (short*)alloc((size_t)L_ * C_ * C_ * 2);
  short* w1T   = (short*)alloc((size_t)L_ * FF_ * C_ * 2);
  short* w2T   = (short*)alloc((size_t)L_ * C_ * FF_ * 2);
  short* headT = (short*)alloc((size_t)VPAD_ * C_ * 2);
  float* qkvb  = (float*)alloc((size_t)L_ * QKVN * 4);
  float* x     = (float*)alloc((size_t)M_ * C_ * 4);
  bf16*  h     = (bf16*)alloc((size_t)M_ * C_ * 2);
  short* qkvB  = (short*)alloc((size_t)M_ * QKVN * 2);
  short* vt    = (short*)alloc((size_t)B_ * H_ * D_ * T_ * 2);
  short* y     = (short*)alloc((size_t)M_ * C_ * 2);
  short* hid   = (short*)alloc((size_t)M_ * FF_ * 2);
  if (off > ws_size) return;

  convt_kernel<<<dim3(12, 12, 12), 256, 0, stream>>>(wq, (bf16*)qkvT, C_, C_, (long)C_ * C_, (long)QKVN * C_, 0);
  convt_kernel<<<dim3(12, 12, 12), 256, 0, stream>>>(wk, (bf16*)qkvT, C_, C_, (long)C_ * C_, (long)QKVN * C_, C_);
  convt_kernel<<<dim3(12, 12, 12), 256, 0, stream>>>(wv, (bf16*)qkvT, C_, C_, (long)C_ * C_, (long)QKVN * C_, 2 * C_);
  convt_kernel<<<dim3(12, 12, 12), 256, 0, stream>>>(wo, (bf16*)woT, C_, C_, (long)C_ * C_, (long)C_ * C_, 0);
  convt_kernel<<<dim3(12, 48, 12), 256, 0, stream>>>(w1, (bf16*)w1T, C_, FF_, (long)C_ * FF_, (long)FF_ * C_, 0);
  convt_kernel<<<dim3(48, 12, 12), 256, 0, stream>>>(w2, (bf16*)w2T, FF_, C_, (long)FF_ * C_, (long)C_ * FF_, 0);
  convt_kernel<<<dim3(12, VPAD_ / 64, 1), 256, 0, stream>>>(headw, (bf16*)headT, C_, V_, 0, 0, 0);
  packb_kernel<<<dim3(108), 256, 0, stream>>>(bq, bk, bv, qkvb);

  embed_kernel<<<dim3(M_), 256, 0, stream>>>(idx, tok, pos, x);

  for (int ly = 0; ly < L_; ly++) {
    ln_kernel<<<dim3(M_ / 4), 256, 0, stream>>>(x, ln1g + ly * C_, ln1b + ly * C_, h);
    gemm64<true, false, false, true, true><<<dim3(64, 18), 256, 0, stream>>>(
        (const short*)h, qkvT + (size_t)ly * QKVN * C_, qkvb + ly * QKVN, nullptr, qkvB, vt, M_, QKVN, C_);
    attn_kernel<<<dim3(16, 48), 256, 0, stream>>>(qkvB, vt, (bf16*)y);
    gemm64<true, false, true, false, false><<<dim3(64, 6), 256, 0, stream>>>(
        y, woT + (size_t)ly * C_ * C_, bo + ly * C_, x, x, nullptr, M_, C_, C_);
    ln_kernel<<<dim3(M_ / 4), 256, 0, stream>>>(x, ln2g + ly * C_, ln2b + ly * C_, h);
    gemm64<true, true, false, true, false><<<dim3(64, 24), 256, 0, stream>>>(
        (const short*)h, w1T + (size_t)ly * FF_ * C_, b1 + ly * FF_, nullptr, hid, nullptr, M_, FF_, C_);
    gemm64<true, false, true, false, false><<<dim3(64, 6), 256, 0, stream>>>(
        hid, w2T + (size_t)ly * C_ * FF_, b2 + ly * C_, x, x, nullptr, M_, C_, FF_);
  }

  ln_kernel<<<dim3(M_ / 4), 256, 0, stream>>>(x, lnfg, lnfb, h);
  gemm256<<<dim3(3200), 512, 0, stream>>>((const short*)h, headT, (float*)d_out, V_, C_);
}

// Round 14
// 3023.849 us; speedup vs baseline: 1.0313x; 1.0313x over previous
//
#include <hip/hip_runtime.h>
#include <hip/hip_bf16.h>
#include <math.h>

#define L_ 12
#define B_ 4
#define T_ 1024
#define C_ 768
#define H_ 12
#define D_ 64
#define V_ 50257
#define M_ 4096
#define QKVN 2304
#define FF_ 3072
#define VPAD_ 51200   // 200 n-tiles of 256 (XCD-partitioned head mapping)

typedef __hip_bfloat16 bf16;
typedef __attribute__((ext_vector_type(4))) float f32x4;
typedef __attribute__((ext_vector_type(4))) short short4v;
typedef __attribute__((ext_vector_type(8))) short short8;
typedef __attribute__((ext_vector_type(8))) __bf16 bf16x8;

typedef __attribute__((address_space(1))) void gvoid;
typedef __attribute__((address_space(3))) void svoid;

__device__ __forceinline__ f32x4 mfma_bf16(short8 a, short8 b, f32x4 c) {
  return __builtin_amdgcn_mfma_f32_16x16x32_bf16(
      __builtin_bit_cast(bf16x8, a), __builtin_bit_cast(bf16x8, b), c, 0, 0, 0);
}

__device__ __forceinline__ void gload_lds16(const void* g, void* l) {
  __builtin_amdgcn_global_load_lds((gvoid*)(void*)g, (svoid*)l, 16, 0, 0);
}

__device__ __forceinline__ short f2bf(float x) {
  return __builtin_bit_cast(short, __float2bfloat16(x));
}

// ---------------- embedding ----------------
__global__ __launch_bounds__(256) void embed_kernel(const int* __restrict__ idx,
    const float* __restrict__ tok, const float* __restrict__ pos, float* __restrict__ x)
{
  const int row = blockIdx.x;
  const int t = row & (T_ - 1);
  const int id = idx[row];
  const float* te = tok + (size_t)id * C_;
  const float* pe = pos + (size_t)t * C_;
  float* xr = x + (size_t)row * C_;
  const int tid = threadIdx.x;
  xr[tid]       = te[tid]       + pe[tid];
  xr[tid + 256] = te[tid + 256] + pe[tid + 256];
  xr[tid + 512] = te[tid + 512] + pe[tid + 512];
}

// ---------------- layernorm: 1 wave/row, float4 loads, shuffle-only reduce ----------------
__global__ __launch_bounds__(256) void ln_kernel(const float* __restrict__ x,
    const float* __restrict__ g, const float* __restrict__ be, bf16* __restrict__ out)
{
  const int w = threadIdx.x >> 6, l = threadIdx.x & 63;
  const int row = blockIdx.x * 4 + w;
  const float* xr = x + (size_t)row * C_;
  f32x4 v[3];
  float s = 0.0f, ss = 0.0f;
#pragma unroll
  for (int p = 0; p < 3; p++) {
    v[p] = *(const f32x4*)&xr[p * 256 + l * 4];
#pragma unroll
    for (int e = 0; e < 4; e++) { s += v[p][e]; ss += v[p][e] * v[p][e]; }
  }
#pragma unroll
  for (int o = 32; o >= 1; o >>= 1) { s += __shfl_xor(s, o, 64); ss += __shfl_xor(ss, o, 64); }
  const float mean = s * (1.0f / C_);
  const float rstd = rsqrtf(ss * (1.0f / C_) - mean * mean + 1e-5f);
  bf16* orow = out + (size_t)row * C_;
#pragma unroll
  for (int p = 0; p < 3; p++) {
    const f32x4 gg = *(const f32x4*)&g[p * 256 + l * 4];
    const f32x4 bb = *(const f32x4*)&be[p * 256 + l * 4];
    short4v o4;
#pragma unroll
    for (int e = 0; e < 4; e++) o4[e] = f2bf((v[p][e] - mean) * rstd * gg[e] + bb[e]);
    *(short4v*)&orow[p * 256 + l * 4] = o4;
  }
}

// ---------------- weight convert + transpose: fp32 [K][N] -> bf16 [N(+pad)][K] ----------------
__global__ __launch_bounds__(256) void convt_kernel(const float* __restrict__ in,
    bf16* __restrict__ out, int K, int N, long in_ls, long out_ls, int row_off)
{
  __shared__ float tile[64][65];
  in  += (size_t)blockIdx.z * in_ls;
  out += (size_t)blockIdx.z * out_ls;
  const int k0 = blockIdx.x * 64, n0 = blockIdx.y * 64;
  const int tid = threadIdx.x;
#pragma unroll
  for (int ph = 0; ph < 4; ph++) {
    const int lk = ph * 16 + (tid >> 4);
    const int ln = (tid & 15) * 4;
    const int gn = n0 + ln;
    const float* src = &in[(size_t)(k0 + lk) * N + gn];
    f32x4 vv;
    if (gn + 4 <= N) {
      vv = *(const f32x4*)src;
    } else {
#pragma unroll
      for (int e = 0; e < 4; e++) vv[e] = (gn + e < N) ? src[e] : 0.0f;
    }
    *(f32x4*)&tile[lk][ln] = vv;
  }
  __syncthreads();
#pragma unroll
  for (int ph = 0; ph < 2; ph++) {
    const int lon = ph * 32 + (tid >> 3);
    const int lok0 = (tid & 7) * 8;
    short8 o;
#pragma unroll
    for (int e = 0; e < 8; e++) o[e] = f2bf(tile[lok0 + e][lon]);
    *(short8*)&out[(size_t)(row_off + n0 + lon) * K + k0 + lok0] = o;
  }
}

// ---------------- pack q/k/v biases into [L][2304] ----------------
__global__ __launch_bounds__(256) void packb_kernel(const float* __restrict__ bq,
    const float* __restrict__ bk, const float* __restrict__ bv, float* __restrict__ out)
{
  const int i = blockIdx.x * 256 + threadIdx.x;
  const int ly = i / QKVN, c = i % QKVN;
  float v;
  if (c < C_)            v = bq[ly * C_ + c];
  else if (c < 2 * C_)   v = bk[ly * C_ + c - C_];
  else                   v = bv[ly * C_ + c - 2 * C_];
  out[i] = v;
}

// ---------------- GEMM 128x128 tile (qkv w/ fused V-transpose, fc1) ----------------
template<bool BIAS, bool GELU, bool RESID, bool BF16OUT, bool VT>
__global__ __launch_bounds__(256) void gemm_bt(
    const short* __restrict__ A, const short* __restrict__ Bt,
    const float* __restrict__ bias, const float* resid,
    void* out, short* __restrict__ vt, int M, int N, int K)
{
  __shared__ short As[128 * 64];
  __shared__ short Bs[128 * 64];
  const int tid = threadIdx.x;
  const int w = tid >> 6, l = tid & 63;
  const int l15 = l & 15, l4 = l >> 4;
  const int wr = w >> 1, wc = w & 1;
  const int nwg = gridDim.x * gridDim.y;
  const int id = blockIdx.y * gridDim.x + blockIdx.x;
  const int chunk = nwg >> 3;
  const int swz = (id & 7) * chunk + (id >> 3);
  const long m0 = (long)(swz % gridDim.x) * 128;
  const long n0 = (long)(swz / gridDim.x) * 128;

  f32x4 acc[4][4] = {};
  const int lrow8 = l >> 3;
  const int lc = l & 7;

  for (int kt = 0; kt < K; kt += 64) {
#pragma unroll
    for (int j = 0; j < 8; j++) {
      const int c = w * 8 + j;
      const int isA = (c < 16);
      const int cc = isA ? c : (c - 16);
      const int row = cc * 8 + lrow8;
      const int colsw = ((lc ^ (row & 7)) << 3);
      const short* gp = (isA ? A + (size_t)(m0 + row) * K : Bt + (size_t)(n0 + row) * K) + kt + colsw;
      short* sp = (isA ? As : Bs) + row * 64 + (lc << 3);
      gload_lds16(gp, sp);
    }
    __syncthreads();
#pragma unroll
    for (int ks = 0; ks < 2; ks++) {
      short8 af[4], bfr[4];
#pragma unroll
      for (int i = 0; i < 4; i++) {
        int row = wr * 64 + i * 16 + l15;
        int cs = (ks * 32 + l4 * 8) ^ ((row & 7) << 3);
        af[i] = *(const short8*)&As[row * 64 + cs];
      }
#pragma unroll
      for (int jn = 0; jn < 4; jn++) {
        int row = wc * 64 + jn * 16 + l15;
        int cs = (ks * 32 + l4 * 8) ^ ((row & 7) << 3);
        bfr[jn] = *(const short8*)&Bs[row * 64 + cs];
      }
#pragma unroll
      for (int i = 0; i < 4; i++)
#pragma unroll
        for (int jn = 0; jn < 4; jn++)
          acc[i][jn] = mfma_bf16(af[i], bfr[jn], acc[i][jn]);
    }
    __syncthreads();
  }

#pragma unroll
  for (int i = 0; i < 4; i++) {
    const long rbase = m0 + wr * 64 + i * 16 + l4 * 4;
#pragma unroll
    for (int jn = 0; jn < 4; jn++) {
      const long col = n0 + wc * 64 + jn * 16 + l15;
      const float bv = BIAS ? bias[col] : 0.0f;
      if (VT && col >= 2 * C_) {
        const int hd = (int)col - 2 * C_;
        const int b = (int)(rbase >> 10);
        const int t0 = (int)(rbase & 1023);
        short4v o4;
#pragma unroll
        for (int r = 0; r < 4; r++) o4[r] = f2bf(acc[i][jn][r] + bv);
        *(short4v*)&vt[((size_t)(b * H_) * D_ + hd) * T_ + t0] = o4;
      } else {
#pragma unroll
        for (int r = 0; r < 4; r++) {
          float v = acc[i][jn][r] + bv;
          if (GELU) v = 0.5f * v * (1.0f + erff(v * 0.70710678118654752f));
          const size_t o = (size_t)(rbase + r) * (size_t)N + col;
          if (RESID)        ((float*)out)[o] = resid[o] + v;
          else if (BF16OUT) ((bf16*)out)[o] = __float2bfloat16(v);
          else              ((float*)out)[o] = v;
        }
      }
    }
  }
}

// ---------------- GEMM 64x128 tile (proj, fc2) ----------------
template<bool BIAS, bool GELU, bool RESID, bool BF16OUT>
__global__ __launch_bounds__(256) void gemm64(
    const short* __restrict__ A, const short* __restrict__ Bt,
    const float* __restrict__ bias, const float* resid,
    void* out, int M, int N, int K)
{
  __shared__ short As[64 * 64];
  __shared__ short Bs[128 * 64];
  const int tid = threadIdx.x;
  const int w = tid >> 6, l = tid & 63;
  const int l15 = l & 15, l4 = l >> 4;
  const int wm = w >> 1, wn = w & 1;
  const int nwg = gridDim.x * gridDim.y;
  const int id = blockIdx.y * gridDim.x + blockIdx.x;
  const int chunk = nwg >> 3;
  const int swz = (id & 7) * chunk + (id >> 3);
  const long m0 = (long)(swz % gridDim.x) * 64;
  const long n0 = (long)(swz / gridDim.x) * 128;
  const int rr = tid >> 3, g = tid & 7;

  f32x4 acc[2][4] = {};

  for (int kt = 0; kt < K; kt += 64) {
#pragma unroll
    for (int p = 0; p < 2; p++) {
      const int row = p * 32 + rr;
      const int cg = ((g ^ (row & 7)) << 3);
      gload_lds16(A + (size_t)(m0 + row) * K + kt + cg, &As[row * 64 + g * 8]);
    }
#pragma unroll
    for (int p = 0; p < 4; p++) {
      const int row = p * 32 + rr;
      const int cg = ((g ^ (row & 7)) << 3);
      gload_lds16(Bt + (size_t)(n0 + row) * K + kt + cg, &Bs[row * 64 + g * 8]);
    }
    __syncthreads();
#pragma unroll
    for (int ks = 0; ks < 2; ks++) {
      short8 af[2], bfr[4];
#pragma unroll
      for (int i = 0; i < 2; i++) {
        int row = wm * 32 + i * 16 + l15;
        int cs = (ks * 32 + l4 * 8) ^ ((row & 7) << 3);
        af[i] = *(const short8*)&As[row * 64 + cs];
      }
#pragma unroll
      for (int j = 0; j < 4; j++) {
        int row = wn * 64 + j * 16 + l15;
        int cs = (ks * 32 + l4 * 8) ^ ((row & 7) << 3);
        bfr[j] = *(const short8*)&Bs[row * 64 + cs];
      }
#pragma unroll
      for (int i = 0; i < 2; i++)
#pragma unroll
        for (int j = 0; j < 4; j++)
          acc[i][j] = mfma_bf16(af[i], bfr[j], acc[i][j]);
    }
    __syncthreads();
  }

#pragma unroll
  for (int i = 0; i < 2; i++) {
    const long rbase = m0 + wm * 32 + i * 16 + l4 * 4;
#pragma unroll
    for (int j = 0; j < 4; j++) {
      const long col = n0 + wn * 64 + j * 16 + l15;
      const float bv = BIAS ? bias[col] : 0.0f;
#pragma unroll
      for (int r = 0; r < 4; r++) {
        float v = acc[i][j][r] + bv;
        if (GELU) v = 0.5f * v * (1.0f + erff(v * 0.70710678118654752f));
        const size_t o = (size_t)(rbase + r) * (size_t)N + col;
        if (RESID)        ((float*)out)[o] = resid[o] + v;
        else if (BF16OUT) ((bf16*)out)[o] = __float2bfloat16(v);
        else              ((float*)out)[o] = v;
      }
    }
  }
}

// ---------------- 256x256 pipelined head GEMM: vmcnt(6) pipeline + XCD m/n partition ----------
__global__ __launch_bounds__(512, 1) void gemm256(
    const short* __restrict__ A, const short* __restrict__ Bt,
    float* __restrict__ out, int N, int K)
{
  __shared__ short As[2][256 * 64];
  __shared__ short Bs[2][256 * 64];
  const int tid = threadIdx.x;
  const int l = tid & 63, l15 = l & 15, l4 = l >> 4;
  const int wv = tid >> 6, wm = wv >> 2, wn = wv & 3;
  const int bid = blockIdx.x;
  const int x = bid & 7, r = bid >> 3;
  const int mt = (x & 1) * 8 + (r & 7);
  const int nt = (x >> 1) * 50 + (r >> 3);
  const long m0 = (long)mt * 256;
  const long n0 = (long)nt * 256;
  const int nkt = K >> 6;
  const int rr = tid >> 3, g = tid & 7;

  f32x4 acc[8][4] = {};

  auto stA = [&](int s, int kt, int off) {
#pragma unroll
    for (int p = 0; p < 2; p++) {
      const int row = p * 128 + off + rr;
      gload_lds16(A + (size_t)(m0 + row) * K + (kt << 6) + ((g ^ (row & 7)) << 3),
                  &As[s][row * 64 + g * 8]);
    }
  };
  auto stB = [&](int s, int kt, int off) {
#pragma unroll
    for (int p = 0; p < 2; p++) {
      const int row = p * 128 + ((rr >> 5) << 6) + (rr & 31) + off;
      gload_lds16(Bt + (size_t)(n0 + row) * K + (kt << 6) + ((g ^ (row & 7)) << 3),
                  &Bs[s][row * 64 + g * 8]);
    }
  };
  auto rdA = [&](int s, int mf, int ks) {
    const int row = wm * 128 + mf * 16 + l15;
    const int cs = (ks * 32 + l4 * 8) ^ ((row & 7) << 3);
    return *(const short8*)&As[s][row * 64 + cs];
  };
  auto rdB = [&](int s, int nf, int ks) {
    const int row = wn * 64 + nf * 16 + l15;
    const int cs = (ks * 32 + l4 * 8) ^ ((row & 7) << 3);
    return *(const short8*)&Bs[s][row * 64 + cs];
  };

  stA(0, 0, 0); stB(0, 0, 0); stA(0, 0, 64); stB(0, 0, 32);

  int q = 0;
  for (int kt = 0; kt < nkt; ++kt, q ^= 1) {
    const int ktn = (kt + 1 < nkt) ? kt + 1 : kt;
    short8 a0[2][4], a1[2][4], b0[2][2], b1[2][2];

    stA(q ^ 1, ktn, 0);
    asm volatile("s_waitcnt vmcnt(6)" ::: "memory");
    __builtin_amdgcn_s_barrier();
#pragma unroll
    for (int ks = 0; ks < 2; ks++) {
#pragma unroll
      for (int f = 0; f < 4; f++) a0[ks][f] = rdA(q, f, ks);
#pragma unroll
      for (int j = 0; j < 2; j++) b0[ks][j] = rdB(q, j, ks);
    }
    __builtin_amdgcn_s_setprio(1);
#pragma unroll
    for (int f = 0; f < 4; f++)
#pragma unroll
      for (int j = 0; j < 2; j++) {
        acc[f][j] = mfma_bf16(a0[0][f], b0[0][j], acc[f][j]);
        acc[f][j] = mfma_bf16(a0[1][f], b0[1][j], acc[f][j]);
      }
    __builtin_amdgcn_s_setprio(0);

    stB(q ^ 1, ktn, 0);
    asm volatile("s_waitcnt vmcnt(6)" ::: "memory");
    __builtin_amdgcn_s_barrier();
#pragma unroll
    for (int ks = 0; ks < 2; ks++)
#pragma unroll
      for (int f = 0; f < 4; f++) a1[ks][f] = rdA(q, f + 4, ks);
    __builtin_amdgcn_s_setprio(1);
#pragma unroll
    for (int f = 0; f < 4; f++)
#pragma unroll
      for (int j = 0; j < 2; j++) {
        acc[f + 4][j] = mfma_bf16(a1[0][f], b0[0][j], acc[f + 4][j]);
        acc[f + 4][j] = mfma_bf16(a1[1][f], b0[1][j], acc[f + 4][j]);
      }
    __builtin_amdgcn_s_setprio(0);

    stA(q ^ 1, ktn, 64);
    asm volatile("s_waitcnt vmcnt(6)" ::: "memory");
    __builtin_amdgcn_s_barrier();
#pragma unroll
    for (int ks = 0; ks < 2; ks++)
#pragma unroll
      for (int j = 0; j < 2; j++) b1[ks][j] = rdB(q, j + 2, ks);
    __builtin_amdgcn_s_setprio(1);
#pragma unroll
    for (int f = 0; f < 4; f++)
#pragma unroll
      for (int j = 0; j < 2; j++) {
        acc[f][j + 2] = mfma_bf16(a0[0][f], b1[0][j], acc[f][j + 2]);
        acc[f][j + 2] = mfma_bf16(a0[1][f], b1[1][j], acc[f][j + 2]);
      }
    __builtin_amdgcn_s_setprio(0);

    stB(q ^ 1, ktn, 32);
    __builtin_amdgcn_s_setprio(1);
#pragma unroll
    for (int f = 0; f < 4; f++)
#pragma unroll
      for (int j = 0; j < 2; j++) {
        acc[f + 4][j + 2] = mfma_bf16(a1[0][f], b1[0][j], acc[f + 4][j + 2]);
        acc[f + 4][j + 2] = mfma_bf16(a1[1][f], b1[1][j], acc[f + 4][j + 2]);
      }
    __builtin_amdgcn_s_setprio(0);
  }

#pragma unroll
  for (int i = 0; i < 8; i++) {
#pragma unroll
    for (int j = 0; j < 4; j++) {
      const long col = n0 + wn * 64 + j * 16 + l15;
      if (col >= N) continue;
#pragma unroll
      for (int r2 = 0; r2 < 4; r2++) {
        const long row = m0 + wm * 128 + i * 16 + l4 * 4 + r2;
        out[(size_t)row * (size_t)N + col] = acc[i][j][r2];
      }
    }
  }
}

// ---------------- flash attention: r11 winner + skip-mask fast path + setprio ----------------
__global__ __launch_bounds__(256) void attn_kernel(const short* __restrict__ qkv,
    const short* __restrict__ vt, bf16* __restrict__ y)
{
  __shared__ short Ks[2][64 * 64];
  __shared__ short Vs[2][64 * 64];
  const int qt = (gridDim.x - 1) - blockIdx.x;
  const int bh = blockIdx.y;
  const int b = bh / H_, h = bh % H_;
  const int tid = threadIdx.x, w = tid >> 6, l = tid & 63;
  const int l15 = l & 15, l4 = l >> 4;
  const int qrow0 = qt * 64 + w * 16;
  const float SC2 = 0.125f * 1.44269504088896f;

  auto stageKV = [&](int s, int s0) {
    const short* kbase = qkv + (size_t)(b * T_ + s0) * QKVN + C_ + h * D_;
    const short* vsrc = vt + (size_t)bh * D_ * T_ + s0;
#pragma unroll
    for (int ph = 0; ph < 2; ph++) {
      int r = ph * 32 + (tid >> 3);
      int gk = ((tid & 7) ^ ((r & 3) | (((r >> 3) & 1) << 2))) << 3;
      int gv = ((tid & 7) ^ (r & 7)) << 3;
      gload_lds16(kbase + (size_t)r * QKVN + gk, &Ks[s][r * 64 + (tid & 7) * 8]);
      gload_lds16(vsrc + (size_t)r * T_ + gv, &Vs[s][r * 64 + (tid & 7) * 8]);
    }
  };

  short8 qf[2];
#pragma unroll
  for (int kf = 0; kf < 2; kf++)
    qf[kf] = *(const short8*)&qkv[(size_t)(b * T_ + qrow0 + l15) * QKVN + h * D_ + kf * 32 + l4 * 8];

  f32x4 O[4] = {};
  float mst = -1e30f, lst = 0.0f;

  stageKV(0, 0);
  __syncthreads();

  int cur = 0;
  const int qg = qrow0 + l15;
  const int send = qt * 64 + 64;
  for (int s0 = 0; s0 < send; s0 += 64) {
    if (s0 + 64 < send) stageKV(cur ^ 1, s0 + 64);
    f32x4 S[4];
    __builtin_amdgcn_s_setprio(1);
#pragma unroll
    for (int c = 0; c < 4; c++) {
      const int row = 8 * (l15 >> 2) + (l15 & 3) + 4 * (c & 1) + 32 * (c >> 1);
      const int swz = (row & 3) | (((row >> 3) & 1) << 2);
      short8 k0 = *(const short8*)&Ks[cur][row * 64 + ((l4 ^ swz) << 3)];
      short8 k1 = *(const short8*)&Ks[cur][row * 64 + (((4 + l4) ^ swz) << 3)];
      f32x4 z = {0.0f, 0.0f, 0.0f, 0.0f};
      z = mfma_bf16(k0, qf[0], z);
      z = mfma_bf16(k1, qf[1], z);
      S[c] = z;
    }
    __builtin_amdgcn_s_setprio(0);
    // scale + causal mask; skip mask entirely for fully-unmasked tiles (wave-uniform)
    if (s0 + 63 <= qrow0) {
#pragma unroll
      for (int c = 0; c < 4; c++)
#pragma unroll
        for (int r = 0; r < 4; r++) S[c][r] *= SC2;
    } else {
#pragma unroll
      for (int c = 0; c < 4; c++) {
        const int kvb = s0 + 8 * l4 + 4 * (c & 1) + 32 * (c >> 1);
#pragma unroll
        for (int r = 0; r < 4; r++) {
          const float v = S[c][r] * SC2;
          S[c][r] = (kvb + r <= qg) ? v : -1e30f;
        }
      }
    }
    float pm = -1e30f;
#pragma unroll
    for (int c = 0; c < 4; c++)
#pragma unroll
      for (int r = 0; r < 4; r++) pm = fmaxf(pm, S[c][r]);
    float mn;
    if (__all(pm - mst <= 8.0f)) {
      mn = mst;
    } else {
      float pm2 = fmaxf(pm, __shfl_xor(pm, 16, 64));
      pm2 = fmaxf(pm2, __shfl_xor(pm2, 32, 64));
      mn = fmaxf(mst, pm2);
      const float al = exp2f(mst - mn);
      mst = mn;
      lst *= al;
#pragma unroll
      for (int r = 0; r < 4; r++) {
        const float alr = __shfl(al, l4 * 4 + r, 16);
#pragma unroll
        for (int df = 0; df < 4; df++) O[df][r] *= alr;
      }
    }
    float rs = 0.0f;
    float pvv[4][4];
#pragma unroll
    for (int c = 0; c < 4; c++)
#pragma unroll
      for (int r = 0; r < 4; r++) { pvv[c][r] = exp2f(S[c][r] - mn); rs += pvv[c][r]; }
    rs += __shfl_xor(rs, 16, 64);
    rs += __shfl_xor(rs, 32, 64);
    lst += rs;
    short8 pa[2];
#pragma unroll
    for (int ks = 0; ks < 2; ks++)
#pragma unroll
      for (int r = 0; r < 4; r++) {
        pa[ks][r]     = f2bf(pvv[2 * ks][r]);
        pa[ks][r + 4] = f2bf(pvv[2 * ks + 1][r]);
      }
    __builtin_amdgcn_s_setprio(1);
#pragma unroll
    for (int df = 0; df < 4; df++) {
      const int row = df * 16 + l15;
      short8 v0 = *(const short8*)&Vs[cur][row * 64 + ((l4 ^ (row & 7)) << 3)];
      short8 v1 = *(const short8*)&Vs[cur][row * 64 + ((((4 + l4)) ^ (row & 7)) << 3)];
      O[df] = mfma_bf16(pa[0], v0, O[df]);
      O[df] = mfma_bf16(pa[1], v1, O[df]);
    }
    __builtin_amdgcn_s_setprio(0);
    __syncthreads();
    cur ^= 1;
  }

  const float inv = 1.0f / lst;
#pragma unroll
  for (int r = 0; r < 4; r++) {
    const float invr = __shfl(inv, l4 * 4 + r, 16);
    const size_t row = (size_t)(b * T_ + qrow0 + l4 * 4 + r);
#pragma unroll
    for (int df = 0; df < 4; df++)
      y[row * C_ + h * D_ + df * 16 + l15] = __float2bfloat16(O[df][r] * invr);
  }
}

// ---------------- host ----------------
extern "C" void kernel_launch(void* const* d_in, const int* in_sizes, int n_in,
                              void* d_out, int out_size, void* d_ws, size_t ws_size,
                              hipStream_t stream)
{
  const int*   idx  = (const int*)d_in[0];
  const float* tok  = (const float*)d_in[1];
  const float* pos  = (const float*)d_in[2];
  const float* wq   = (const float*)d_in[3];
  const float* bq   = (const float*)d_in[4];
  const float* wk   = (const float*)d_in[5];
  const float* bk   = (const float*)d_in[6];
  const float* wv   = (const float*)d_in[7];
  const float* bv   = (const float*)d_in[8];
  const float* wo   = (const float*)d_in[9];
  const float* bo   = (const float*)d_in[10];
  const float* ln1g = (const float*)d_in[11];
  const float* ln1b = (const float*)d_in[12];
  const float* ln2g = (const float*)d_in[13];
  const float* ln2b = (const float*)d_in[14];
  const float* w1   = (const float*)d_in[15];
  const float* b1   = (const float*)d_in[16];
  const float* w2   = (const float*)d_in[17];
  const float* b2   = (const float*)d_in[18];
  const float* lnfg = (const float*)d_in[19];
  const float* lnfb = (const float*)d_in[20];
  const float* headw= (const float*)d_in[21];

  char* p = (char*)d_ws;
  size_t off = 0;
  auto alloc = [&](size_t n) { void* r = p + off; off += (n + 255) & ~(size_t)255; return r; };
  short* qkvT  = (short*)alloc((size_t)L_ * QKVN * C_ * 2);
  short* woT   = (short*)alloc((size_t)L_ * C_ * C_ * 2);
  short* w1T   = (short*)alloc((size_t)L_ * FF_ * C_ * 2);
  short* w2T   = (short*)alloc((size_t)L_ * C_ * FF_ * 2);
  short* headT = (short*)alloc((size_t)VPAD_ * C_ * 2);
  float* qkvb  = (float*)alloc((size_t)L_ * QKVN * 4);
  float* x     = (float*)alloc((size_t)M_ * C_ * 4);
  bf16*  h     = (bf16*)alloc((size_t)M_ * C_ * 2);
  short* qkvB  = (short*)alloc((size_t)M_ * QKVN * 2);
  short* vt    = (short*)alloc((size_t)B_ * H_ * D_ * T_ * 2);
  short* y     = (short*)alloc((size_t)M_ * C_ * 2);
  short* hid   = (short*)alloc((size_t)M_ * FF_ * 2);
  if (off > ws_size) return;

  convt_kernel<<<dim3(12, 12, 12), 256, 0, stream>>>(wq, (bf16*)qkvT, C_, C_, (long)C_ * C_, (long)QKVN * C_, 0);
  convt_kernel<<<dim3(12, 12, 12), 256, 0, stream>>>(wk, (bf16*)qkvT, C_, C_, (long)C_ * C_, (long)QKVN * C_, C_);
  convt_kernel<<<dim3(12, 12, 12), 256, 0, stream>>>(wv, (bf16*)qkvT, C_, C_, (long)C_ * C_, (long)QKVN * C_, 2 * C_);
  convt_kernel<<<dim3(12, 12, 12), 256, 0, stream>>>(wo, (bf16*)woT, C_, C_, (long)C_ * C_, (long)C_ * C_, 0);
  convt_kernel<<<dim3(12, 48, 12), 256, 0, stream>>>(w1, (bf16*)w1T, C_, FF_, (long)C_ * FF_, (long)FF_ * C_, 0);
  convt_kernel<<<dim3(48, 12, 12), 256, 0, stream>>>(w2, (bf16*)w2T, FF_, C_, (long)FF_ * C_, (long)C_ * FF_, 0);
  convt_kernel<<<dim3(12, VPAD_ / 64, 1), 256, 0, stream>>>(headw, (bf16*)headT, C_, V_, 0, 0, 0);
  packb_kernel<<<dim3(108), 256, 0, stream>>>(bq, bk, bv, qkvb);

  embed_kernel<<<dim3(M_), 256, 0, stream>>>(idx, tok, pos, x);

  for (int ly = 0; ly < L_; ly++) {
    ln_kernel<<<dim3(M_ / 4), 256, 0, stream>>>(x, ln1g + ly * C_, ln1b + ly * C_, h);
    gemm_bt<true, false, false, true, true><<<dim3(32, 18), 256, 0, stream>>>(
        (const short*)h, qkvT + (size_t)ly * QKVN * C_, qkvb + ly * QKVN, nullptr, qkvB, vt, M_, QKVN, C_);
    attn_kernel<<<dim3(16, 48), 256, 0, stream>>>(qkvB, vt, (bf16*)y);
    gemm64<true, false, true, false><<<dim3(64, 6), 256, 0, stream>>>(
        y, woT + (size_t)ly * C_ * C_, bo + ly * C_, x, x, M_, C_, C_);
    ln_kernel<<<dim3(M_ / 4), 256, 0, stream>>>(x, ln2g + ly * C_, ln2b + ly * C_, h);
    gemm_bt<true, true, false, true, false><<<dim3(32, 24), 256, 0, stream>>>(
        (const short*)h, w1T + (size_t)ly * FF_ * C_, b1 + ly * FF_, nullptr, hid, nullptr, M_, FF_, C_);
    gemm64<true, false, true, false><<<dim3(64, 6), 256, 0, stream>>>(
        hid, w2T + (size_t)ly * C_ * FF_, b2 + ly * C_, x, x, M_, C_, FF_);
  }

  ln_kernel<<<dim3(M_ / 4), 256, 0, stream>>>(x, lnfg, lnfb, h);
  gemm256<<<dim3(3200), 512, 0, stream>>>((const short*)h, headT, (float*)d_out, V_, C_);
}